// Round 7
// baseline (226.751 us; speedup 1.0000x reference)
//
#include <hip/hip_runtime.h>

#define NB 16
#define NTQ 256
#define NTK 256
#define ND 256
#define NF 36
#define NH 8
#define NDK 32
#define NSF 6

typedef __attribute__((ext_vector_type(8))) short short8;
typedef __attribute__((ext_vector_type(4))) float f32x4;
#define MFMA16(a,b,c) __builtin_amdgcn_mfma_f32_16x16x32_bf16(a,b,c,0,0,0)

// ---- workspace byte offsets ----
#define SZ_QP  (16*8*256*32*2)
#define QPH_OFF 0
#define QPL_OFF (QPH_OFF + SZ_QP)
#define KPH_OFF (QPL_OFF + SZ_QP)
#define KPL_OFF (KPH_OFF + SZ_QP)
#define SZ_RT  (16*80*256*2)
#define RT_OFF  (KPL_OFF + SZ_QP)
#define HD_OFF  (RT_OFF + SZ_RT)                 // fp32 [16][8][256][36]
// total ~21.5 MB

__device__ __forceinline__ short f2bf(float x){
    union { float f; unsigned u; } v; v.f = x;
    unsigned r = v.u + 0x7fffu + ((v.u >> 16) & 1u);
    return (short)(r >> 16);
}
__device__ __forceinline__ float bf2f(short s){
    union { float f; unsigned u; } v; v.u = ((unsigned)(unsigned short)s) << 16;
    return v.f;
}
__device__ __forceinline__ float fast_tanh(float x){
    float e = __expf(2.0f*x);
    return 1.0f - 2.0f/(e + 1.0f);
}
__device__ __forceinline__ short8 ld8(const short* p){ return *(const short8*)p; }

// hi/lo bf16 split of 8 consecutive floats (RNE hi, RNE residual lo)
__device__ __forceinline__ void cvt8(const float* __restrict__ p, short8& h8, short8& l8){
    f32x4 a = *(const f32x4*)p;
    f32x4 c = *(const f32x4*)(p + 4);
    #pragma unroll
    for (int i = 0; i < 4; ++i){
        short h0 = f2bf(a[i]); h8[i]   = h0; l8[i]   = f2bf(a[i] - bf2f(h0));
        short h1 = f2bf(c[i]); h8[4+i] = h1; l8[4+i] = f2bf(c[i] - bf2f(h1));
    }
}

// ---------------- kernel 1: fused pack + projections ----------------
__global__ void imta_prep(const float* __restrict__ query, const float* __restrict__ key_ts,
                          const float* __restrict__ Wq, const float* __restrict__ Wk,
                          const float* __restrict__ mask, const float* __restrict__ value,
                          char* __restrict__ wsb){
    if (blockIdx.y == 2){
        const int b = blockIdx.z, k = threadIdx.x;
        short* rt = (short*)(wsb + RT_OFF) + b*80*256;
        #pragma unroll
        for (int r = 0; r < 5; ++r){
            const int fp = blockIdx.x*5 + r;
            const int f = fp >> 1;
            short o = 0;
            if (f < NF){
                float m = mask[(b*NTK + k)*NF + f];
                o = (fp & 1) ? f2bf(m) : f2bf(m * value[(b*NTK + k)*NF + f]);
            }
            rt[fp*256 + k] = o;
        }
        return;
    }
    const int side = blockIdx.y, b = blockIdx.z;
    const int mt = blockIdx.x >> 1, nh = blockIdx.x & 1;
    const int t0 = mt*32;
    const int tid = threadIdx.x, w = tid >> 6, lane = tid & 63;
    const int col = lane & 15, quad = lane >> 4;
    const float* __restrict__ X = side ? key_ts : query;
    const float* __restrict__ W = side ? Wk : Wq;
    __shared__ float sX[32][36];
    __shared__ float sW[128][36];
    const int xr = tid >> 3, xc = (tid & 7)*4;
    const int dr = tid >> 3, dkq = (tid & 7)*4;
    f32x4 acc[2][2];
    #pragma unroll
    for (int m = 0; m < 2; ++m){ acc[m][0] = (f32x4)0.f; acc[m][1] = (f32x4)0.f; }
    for (int kb = 0; kb < 8; ++kb){
        const int dc = kb*32;
        float4 xv = *(const float4*)(X + (size_t)(b*NTQ + t0 + xr)*ND + dc + xc);
        float4 wv[4];
        #pragma unroll
        for (int jj = 0; jj < 4; ++jj)
            wv[jj] = *(const float4*)(W + (size_t)((4*nh + jj)*ND + dc + dr)*NDK + dkq);
        __syncthreads();
        *(float4*)&sX[xr][xc] = xv;
        #pragma unroll
        for (int jj = 0; jj < 4; ++jj)
            #pragma unroll
            for (int i = 0; i < 4; ++i)
                sW[jj*32 + dkq + i][dr] = ((const float*)&wv[jj])[i];
        __syncthreads();
        short8 ah[2], al[2], bh[2], bl[2];
        #pragma unroll
        for (int m = 0; m < 2; ++m)
            cvt8(&sX[m*16 + col][quad*8], ah[m], al[m]);
        #pragma unroll
        for (int nt = 0; nt < 2; ++nt)
            cvt8(&sW[(w*2 + nt)*16 + col][quad*8], bh[nt], bl[nt]);
        #pragma unroll
        for (int m = 0; m < 2; ++m)
            #pragma unroll
            for (int nt = 0; nt < 2; ++nt){
                acc[m][nt] = MFMA16(al[m], bh[nt], acc[m][nt]);
                acc[m][nt] = MFMA16(ah[m], bl[nt], acc[m][nt]);
                acc[m][nt] = MFMA16(ah[m], bh[nt], acc[m][nt]);
            }
    }
    short* oh = (short*)(wsb + (side ? KPH_OFF : QPH_OFF));
    short* ol = (short*)(wsb + (side ? KPL_OFF : QPL_OFF));
    #pragma unroll
    for (int m = 0; m < 2; ++m)
        #pragma unroll
        for (int nt = 0; nt < 2; ++nt){
            const int n = (nh*8 + w*2 + nt)*16 + col;
            const int j = n >> 5, dk = n & 31;
            #pragma unroll
            for (int r = 0; r < 4; ++r){
                const int t = t0 + m*16 + quad*4 + r;
                float v = acc[m][nt][r];
                short h = f2bf(v);
                size_t o = (size_t)(((b*NH + j)*NTQ + t)*NDK + dk);
                oh[o] = h; ol[o] = f2bf(v - bf2f(h));
            }
        }
}

// ---------------- kernel 2: attention via MFMA, 32-row q tiles ----------------
// grid (8,8,16) = 1024 blocks, LDS 16.9 KB -> 4 blocks/CU resident.
__global__ void imta_attn(char* __restrict__ wsb, const float* __restrict__ value){
    const int t0 = blockIdx.x*32;
    const int j = blockIdx.y, b = blockIdx.z;
    const int tid = threadIdx.x, w = tid >> 6, lane = tid & 63;
    const int col = lane & 15, quad = lane >> 4;
    __shared__ short sE[32*264];               // 16.9 KB; reused for sH
    const short* QH = (const short*)(wsb + QPH_OFF) + (b*NH + j)*NTQ*NDK;
    const short* QL = (const short*)(wsb + QPL_OFF) + (b*NH + j)*NTQ*NDK;
    const short* KH = (const short*)(wsb + KPH_OFF) + (b*NH + j)*NTK*NDK;
    const short* KL = (const short*)(wsb + KPL_OFF) + (b*NH + j)*NTK*NDK;
    const short* RT = (const short*)(wsb + RT_OFF) + b*80*256;
    float* HD = (float*)(wsb + HD_OFF) + (b*NH + j)*NTQ*NF;

    // ---- phase B1: wave w covers keys [64w,64w+64); rows t0..t0+31 ----
    short8 ah[2], al[2];
    #pragma unroll
    for (int m = 0; m < 2; ++m){
        const int t = t0 + m*16 + col;
        ah[m] = ld8(QH + t*NDK + quad*8);
        al[m] = ld8(QL + t*NDK + quad*8);
    }
    #pragma unroll
    for (int nt = 0; nt < 4; ++nt){
        const int key0 = w*64 + nt*16;
        short8 bh = ld8(KH + (key0 + col)*NDK + quad*8);
        short8 bl = ld8(KL + (key0 + col)*NDK + quad*8);
        f32x4 acc[2];
        #pragma unroll
        for (int m = 0; m < 2; ++m){
            f32x4 c = (f32x4)0.f;
            c = MFMA16(al[m], bh, c);
            c = MFMA16(ah[m], bl, c);
            c = MFMA16(ah[m], bh, c);
            acc[m] = c;
        }
        const int key = key0 + col;
        #pragma unroll
        for (int m = 0; m < 2; ++m)
            #pragma unroll
            for (int r = 0; r < 4; ++r){
                const int q = m*16 + quad*4 + r;
                sE[q*264 + key] = f2bf(__expf(acc[m][r]));
            }
    }
    __syncthreads();

    // ---- phase B2: wave w -> q-half (w&1), f-tiles {0,1,2} (w<2) or {3,4} ----
    const int q0 = (w & 1)*16;
    const int ntbase = (w >> 1) ? 3 : 0;
    const int ntcnt  = (w >> 1) ? 2 : 3;
    f32x4 acc2[3];
    #pragma unroll
    for (int t = 0; t < 3; ++t) acc2[t] = (f32x4)0.f;
    #pragma unroll 2
    for (int kb = 0; kb < 8; ++kb){
        const int ko = kb*32 + quad*8;
        short8 a = *(const short8*)&sE[(q0 + col)*264 + ko];
        #pragma unroll
        for (int t = 0; t < 3; ++t)
            if (t < ntcnt){
                short8 bb = ld8(RT + ((ntbase + t)*16 + col)*256 + ko);
                acc2[t] = MFMA16(a, bb, acc2[t]);
            }
    }
    __syncthreads();                           // all sE reads done before overlay
    float* sH = (float*)sE;                    // [32][40] heads staging
    #pragma unroll
    for (int t = 0; t < 3; ++t)
        if (t < ntcnt)
            #pragma unroll
            for (int r = 0; r < 4; ++r){
                float v = acc2[t][r];
                float o = __shfl_xor(v, 1, 64);
                if (!(col & 1)){
                    const int f = (ntbase + t)*8 + (col >> 1);
                    if (f < NF){
                        float num = v, den = o, h;
                        if (den != 0.0f) h = num/den;
                        else {
                            float s = 0.f;
                            for (int k = 0; k < NTK; ++k) s += value[(b*NTK + k)*NF + f];
                            h = s * (1.0f/256.0f);
                        }
                        sH[(q0 + quad*4 + r)*40 + f] = h;
                    }
                }
            }
    __syncthreads();
    for (int idx = tid; idx < 32*NF; idx += 256){
        const int q = idx/NF, f = idx - q*NF;
        HD[(t0 + q)*NF + f] = sH[q*40 + f];
    }
}

// ---------------- kernel 3: fused head-mix MLP, 4 q per block ----------------
__global__ void imta_final(const float* __restrict__ Wc, const float* __restrict__ bc,
                           const float* __restrict__ Wo1, const float* __restrict__ bo1,
                           const float* __restrict__ Wo2, const float* __restrict__ bo2,
                           const float* __restrict__ hd, float* __restrict__ out){
    const int b = blockIdx.x >> 6, q0 = (blockIdx.x & 63)*4;
    const int tid = threadIdx.x;
    __shared__ float sh[4*NF*NH];              // [r][h][f]
    __shared__ float sW1[NF*NSF];
    for (int t = tid; t < 4*NF*NH; t += 256){
        int r = t/(NF*NH), rem = t - r*(NF*NH);
        int jj = rem/NF, f = rem - jj*NF;
        sh[t] = hd[((b*NH + jj)*NTQ + q0 + r)*NF + f];
    }
    if (tid < NF*NSF) sW1[tid] = Wo1[tid];
    __syncthreads();
    const int d = tid;
    float wcr[8];
    #pragma unroll
    for (int h = 0; h < 8; ++h) wcr[h] = Wc[h*ND + d];
    const float bcd = bc[d], bod = bo2[d];
    float b1[6], w2[6];
    #pragma unroll
    for (int s = 0; s < 6; ++s){ b1[s] = bo1[s]; w2[s] = Wo2[s]; }
    for (int r = 0; r < 4; ++r){
        const float* __restrict__ shr = &sh[r*NF*NH];
        float a2[6];
        #pragma unroll
        for (int s = 0; s < 6; ++s) a2[s] = b1[s];
        #pragma unroll
        for (int f4 = 0; f4 < NF; f4 += 4){
            float4 sv[8];
            #pragma unroll
            for (int h = 0; h < 8; ++h) sv[h] = *(const float4*)&shr[h*NF + f4];
            #pragma unroll
            for (int fi = 0; fi < 4; ++fi){
                float a = bcd;
                #pragma unroll
                for (int h = 0; h < 8; ++h)
                    a = fmaf(reinterpret_cast<const float*>(&sv[h])[fi], wcr[h], a);
                float lf = fast_tanh(a);
                const int f = f4 + fi;
                #pragma unroll
                for (int s = 0; s < 6; ++s)
                    a2[s] = fmaf(lf, sW1[f*NSF + s], a2[s]);
            }
        }
        float o = bod;
        #pragma unroll
        for (int s = 0; s < 6; ++s)
            o = fmaf(fast_tanh(a2[s]), w2[s], o);
        out[(b*NTQ + q0 + r)*ND + d] = o;
    }
}

extern "C" void kernel_launch(void* const* d_in, const int* in_sizes, int n_in,
                              void* d_out, int out_size, void* d_ws, size_t ws_size,
                              hipStream_t stream){
    const float* query  = (const float*)d_in[0];
    const float* key_ts = (const float*)d_in[1];
    const float* value  = (const float*)d_in[2];
    const float* mask   = (const float*)d_in[3];
    const float* Wq     = (const float*)d_in[4];
    const float* Wk     = (const float*)d_in[5];
    const float* Wc     = (const float*)d_in[6];
    const float* bc     = (const float*)d_in[7];
    const float* Wo1    = (const float*)d_in[8];
    const float* bo1    = (const float*)d_in[9];
    const float* Wo2    = (const float*)d_in[10];
    const float* bo2    = (const float*)d_in[11];
    char* wsb  = (char*)d_ws;
    float* out = (float*)d_out;
    (void)in_sizes; (void)n_in; (void)out_size; (void)ws_size;

    imta_prep <<<dim3(16, 3, 16), dim3(256), 0, stream>>>(query, key_ts, Wq, Wk,
                                                          mask, value, wsb);
    imta_attn <<<dim3(8, 8, 16),  dim3(256), 0, stream>>>(wsb, value);
    imta_final<<<dim3(1024),      dim3(256), 0, stream>>>(Wc, bc, Wo1, bo1, Wo2, bo2,
                                                          (const float*)(wsb + HD_OFF), out);
}

// Round 8
// 142.963 us; speedup vs baseline: 1.5861x; 1.5861x over previous
//
#include <hip/hip_runtime.h>

#define NB 16
#define NTQ 256
#define NTK 256
#define ND 256
#define NF 36
#define NH 8
#define NDK 32
#define NSF 6

typedef __attribute__((ext_vector_type(8))) short short8;
typedef __attribute__((ext_vector_type(4))) float f32x4;
#define MFMA16(a,b,c) __builtin_amdgcn_mfma_f32_16x16x32_bf16(a,b,c,0,0,0)

// ---- workspace byte offsets ----
#define SZ_QP  (16*8*256*32*2)
#define QPH_OFF 0
#define QPL_OFF (QPH_OFF + SZ_QP)
#define KPH_OFF (QPL_OFF + SZ_QP)
#define KPL_OFF (KPH_OFF + SZ_QP)
#define SZ_RT  (16*80*256*2)
#define RT_OFF  (KPL_OFF + SZ_QP)
#define HD_OFF  (RT_OFF + SZ_RT)         // fp32 [16][8][256][36]
// total ~21.5 MB

__device__ __forceinline__ short f2bf(float x){
    union { float f; unsigned u; } v; v.f = x;
    unsigned r = v.u + 0x7fffu + ((v.u >> 16) & 1u);
    return (short)(r >> 16);
}
__device__ __forceinline__ float bf2f(short s){
    union { float f; unsigned u; } v; v.u = ((unsigned)(unsigned short)s) << 16;
    return v.f;
}
__device__ __forceinline__ float fast_tanh(float x){
    float e = __expf(2.0f*x);
    return 1.0f - 2.0f/(e + 1.0f);
}
__device__ __forceinline__ short8 ld8(const short* p){ return *(const short8*)p; }

// hi/lo bf16 split of 8 consecutive floats (RNE hi, RNE residual lo)
__device__ __forceinline__ void cvt8(const float* __restrict__ p, short8& h8, short8& l8){
    f32x4 a = *(const f32x4*)p;
    f32x4 c = *(const f32x4*)(p + 4);
    #pragma unroll
    for (int i = 0; i < 4; ++i){
        short h0 = f2bf(a[i]); h8[i]   = h0; l8[i]   = f2bf(a[i] - bf2f(h0));
        short h1 = f2bf(c[i]); h8[4+i] = h1; l8[4+i] = f2bf(c[i] - bf2f(h1));
    }
}

// ---------------- kernel 1: fused pack + projections ----------------
// y in {0,1}: proj side=y. x encodes (mt 0..7 -> 32-row tile, nh 0..1 -> 128-col half).
// y == 2: pack RT[b][f'][k] (f'=2f: bf16(m*v), f'=2f+1: bf16(m), f'>=72: 0), x*5+r rows.
__global__ void imta_prep(const float* __restrict__ query, const float* __restrict__ key_ts,
                          const float* __restrict__ Wq, const float* __restrict__ Wk,
                          const float* __restrict__ mask, const float* __restrict__ value,
                          char* __restrict__ wsb){
    if (blockIdx.y == 2){
        const int b = blockIdx.z, k = threadIdx.x;
        short* rt = (short*)(wsb + RT_OFF) + b*80*256;
        #pragma unroll
        for (int r = 0; r < 5; ++r){
            const int fp = blockIdx.x*5 + r;
            const int f = fp >> 1;
            short o = 0;
            if (f < NF){
                float m = mask[(b*NTK + k)*NF + f];
                o = (fp & 1) ? f2bf(m) : f2bf(m * value[(b*NTK + k)*NF + f]);
            }
            rt[fp*256 + k] = o;
        }
        return;
    }
    const int side = blockIdx.y, b = blockIdx.z;
    const int mt = blockIdx.x >> 1, nh = blockIdx.x & 1;
    const int t0 = mt*32;
    const int tid = threadIdx.x, w = tid >> 6, lane = tid & 63;
    const int col = lane & 15, quad = lane >> 4;
    const float* __restrict__ X = side ? key_ts : query;
    const float* __restrict__ W = side ? Wk : Wq;
    __shared__ float sX[32][36];
    __shared__ float sW[128][36];
    const int xr = tid >> 3, xc = (tid & 7)*4;
    const int dr = tid >> 3, dkq = (tid & 7)*4;
    f32x4 acc[2][2];
    #pragma unroll
    for (int m = 0; m < 2; ++m){ acc[m][0] = (f32x4)0.f; acc[m][1] = (f32x4)0.f; }
    for (int kb = 0; kb < 8; ++kb){
        const int dc = kb*32;
        float4 xv = *(const float4*)(X + (size_t)(b*NTQ + t0 + xr)*ND + dc + xc);
        float4 wv[4];
        #pragma unroll
        for (int jj = 0; jj < 4; ++jj)
            wv[jj] = *(const float4*)(W + (size_t)((4*nh + jj)*ND + dc + dr)*NDK + dkq);
        __syncthreads();
        *(float4*)&sX[xr][xc] = xv;
        #pragma unroll
        for (int jj = 0; jj < 4; ++jj)
            #pragma unroll
            for (int i = 0; i < 4; ++i)
                sW[jj*32 + dkq + i][dr] = ((const float*)&wv[jj])[i];
        __syncthreads();
        short8 ah[2], al[2], bh[2], bl[2];
        #pragma unroll
        for (int m = 0; m < 2; ++m)
            cvt8(&sX[m*16 + col][quad*8], ah[m], al[m]);
        #pragma unroll
        for (int nt = 0; nt < 2; ++nt)
            cvt8(&sW[(w*2 + nt)*16 + col][quad*8], bh[nt], bl[nt]);
        #pragma unroll
        for (int m = 0; m < 2; ++m)
            #pragma unroll
            for (int nt = 0; nt < 2; ++nt){
                acc[m][nt] = MFMA16(al[m], bh[nt], acc[m][nt]);
                acc[m][nt] = MFMA16(ah[m], bl[nt], acc[m][nt]);
                acc[m][nt] = MFMA16(ah[m], bh[nt], acc[m][nt]);
            }
    }
    short* oh = (short*)(wsb + (side ? KPH_OFF : QPH_OFF));
    short* ol = (short*)(wsb + (side ? KPL_OFF : QPL_OFF));
    #pragma unroll
    for (int m = 0; m < 2; ++m)
        #pragma unroll
        for (int nt = 0; nt < 2; ++nt){
            const int n = (nh*8 + w*2 + nt)*16 + col;
            const int j = n >> 5, dk = n & 31;
            #pragma unroll
            for (int r = 0; r < 4; ++r){
                const int t = t0 + m*16 + quad*4 + r;
                float v = acc[m][nt][r];
                short h = f2bf(v);
                size_t o = (size_t)(((b*NH + j)*NTQ + t)*NDK + dk);
                oh[o] = h; ol[o] = f2bf(v - bf2f(h));
            }
        }
}

// ---------------- kernel 2: attention via MFMA ----------------
// block: (qtile | j | b). phase1: scores (hi/lo 3-pass) -> exp -> E(bf16) in LDS
// phase2: E @ RT^T (interleaved mv/m cols) -> shfl div -> heads
__global__ void imta_attn(char* __restrict__ wsb, const float* __restrict__ value){
    const int t0 = blockIdx.x*64;
    const int j = blockIdx.y, b = blockIdx.z;
    const int tid = threadIdx.x, w = tid >> 6, lane = tid & 63;
    const int col = lane & 15, quad = lane >> 4;
    __shared__ short sE[64*264];               // 33.8 KB; later overlaid by sH
    const short* QH = (const short*)(wsb + QPH_OFF) + (b*NH + j)*NTQ*NDK;
    const short* QL = (const short*)(wsb + QPL_OFF) + (b*NH + j)*NTQ*NDK;
    const short* KH = (const short*)(wsb + KPH_OFF) + (b*NH + j)*NTK*NDK;
    const short* KL = (const short*)(wsb + KPL_OFF) + (b*NH + j)*NTK*NDK;
    const short* RT = (const short*)(wsb + RT_OFF) + b*80*256;
    float* HD = (float*)(wsb + HD_OFF) + (b*NH + j)*NTQ*NF;

    // phase 1: wave w covers keys [64w, 64w+64)
    short8 ah[4], al[4];
    #pragma unroll
    for (int m = 0; m < 4; ++m){
        const int t = t0 + m*16 + col;
        ah[m] = ld8(QH + t*NDK + quad*8);
        al[m] = ld8(QL + t*NDK + quad*8);
    }
    #pragma unroll
    for (int nt = 0; nt < 4; ++nt){
        const int key0 = w*64 + nt*16;
        short8 bh = ld8(KH + (key0 + col)*NDK + quad*8);
        short8 bl = ld8(KL + (key0 + col)*NDK + quad*8);
        f32x4 acc[4];
        #pragma unroll
        for (int m = 0; m < 4; ++m){
            f32x4 c = (f32x4)0.f;
            c = MFMA16(al[m], bh, c);
            c = MFMA16(ah[m], bl, c);
            c = MFMA16(ah[m], bh, c);
            acc[m] = c;
        }
        const int key = key0 + col;
        #pragma unroll
        for (int m = 0; m < 4; ++m)
            #pragma unroll
            for (int r = 0; r < 4; ++r){
                const int q = m*16 + quad*4 + r;
                sE[q*264 + key] = f2bf(__expf(acc[m][r]));
            }
    }
    __syncthreads();

    // phase 2: wave w owns q-range [16w, 16w+16)
    const int q0 = w*16;
    f32x4 acc2[5];
    #pragma unroll
    for (int nt = 0; nt < 5; ++nt) acc2[nt] = (f32x4)0.f;
    #pragma unroll 2
    for (int kb = 0; kb < 8; ++kb){
        const int ko = kb*32 + quad*8;
        short8 a = *(const short8*)&sE[(q0 + col)*264 + ko];
        #pragma unroll
        for (int nt = 0; nt < 5; ++nt){
            short8 bb = ld8(RT + (nt*16 + col)*256 + ko);
            acc2[nt] = MFMA16(a, bb, acc2[nt]);
        }
    }
    __syncthreads();                           // all phase-2 sE reads done
    float* sH = (float*)sE;                    // [64][40] heads staging
    #pragma unroll
    for (int nt = 0; nt < 5; ++nt)
        #pragma unroll
        for (int r = 0; r < 4; ++r){
            float v = acc2[nt][r];
            float o = __shfl_xor(v, 1, 64);
            if (!(col & 1)){
                const int f = nt*8 + (col >> 1);
                if (f < NF){
                    float num = v, den = o, h;
                    if (den != 0.0f) h = num/den;
                    else {
                        float s = 0.f;
                        for (int k = 0; k < NTK; ++k) s += value[(b*NTK + k)*NF + f];
                        h = s * (1.0f/256.0f);
                    }
                    sH[(q0 + quad*4 + r)*40 + f] = h;
                }
            }
        }
    __syncthreads();
    for (int idx = tid; idx < 64*NF; idx += 256){
        const int q = idx/NF, f = idx - q*NF;
        HD[(t0 + q)*NF + f] = sH[q*40 + f];
    }
}

// ---------------- kernel 3: fused head-mix MLP ----------------
__global__ void imta_final(const float* __restrict__ Wc, const float* __restrict__ bc,
                           const float* __restrict__ Wo1, const float* __restrict__ bo1,
                           const float* __restrict__ Wo2, const float* __restrict__ bo2,
                           const float* __restrict__ hd, float* __restrict__ out){
    const int bq = blockIdx.x;
    const int b = bq >> 8, qq = bq & 255;
    const int tid = threadIdx.x;
    __shared__ float sh[NF*NH];
    __shared__ float sW1[NF*NSF];
    for (int t = tid; t < NF*NH; t += 256){
        int jj = t/NF, f = t - jj*NF;
        sh[t] = hd[((b*NH + jj)*NTQ + qq)*NF + f];
    }
    if (tid < NF*NSF) sW1[tid] = Wo1[tid];
    __syncthreads();
    const int d = tid;
    float wcr[8];
    #pragma unroll
    for (int h = 0; h < 8; ++h) wcr[h] = Wc[h*ND + d];
    const float bcd = bc[d];
    float a2[6];
    #pragma unroll
    for (int s = 0; s < 6; ++s) a2[s] = bo1[s];
    #pragma unroll
    for (int f4 = 0; f4 < NF; f4 += 4){
        float4 sv[8];
        #pragma unroll
        for (int h = 0; h < 8; ++h) sv[h] = *(const float4*)&sh[h*NF + f4];
        #pragma unroll
        for (int fi = 0; fi < 4; ++fi){
            float a = bcd;
            #pragma unroll
            for (int h = 0; h < 8; ++h)
                a = fmaf(reinterpret_cast<const float*>(&sv[h])[fi], wcr[h], a);
            float lf = fast_tanh(a);
            const int f = f4 + fi;
            #pragma unroll
            for (int s = 0; s < 6; ++s)
                a2[s] = fmaf(lf, sW1[f*NSF + s], a2[s]);
        }
    }
    float o = bo2[d];
    #pragma unroll
    for (int s = 0; s < 6; ++s)
        o = fmaf(fast_tanh(a2[s]), Wo2[s], o);
    out[(b*NTQ + qq)*ND + d] = o;
}

extern "C" void kernel_launch(void* const* d_in, const int* in_sizes, int n_in,
                              void* d_out, int out_size, void* d_ws, size_t ws_size,
                              hipStream_t stream){
    const float* query  = (const float*)d_in[0];
    const float* key_ts = (const float*)d_in[1];
    const float* value  = (const float*)d_in[2];
    const float* mask   = (const float*)d_in[3];
    const float* Wq     = (const float*)d_in[4];
    const float* Wk     = (const float*)d_in[5];
    const float* Wc     = (const float*)d_in[6];
    const float* bc     = (const float*)d_in[7];
    const float* Wo1    = (const float*)d_in[8];
    const float* bo1    = (const float*)d_in[9];
    const float* Wo2    = (const float*)d_in[10];
    const float* bo2    = (const float*)d_in[11];
    char* wsb  = (char*)d_ws;
    float* out = (float*)d_out;
    (void)in_sizes; (void)n_in; (void)out_size; (void)ws_size;

    imta_prep <<<dim3(16, 3, 16), dim3(256), 0, stream>>>(query, key_ts, Wq, Wk,
                                                          mask, value, wsb);
    imta_attn <<<dim3(4, 8, 16),  dim3(256), 0, stream>>>(wsb, value);
    imta_final<<<dim3(4096),      dim3(256), 0, stream>>>(Wc, bc, Wo1, bo1, Wo2, bo2,
                                                          (const float*)(wsb + HD_OFF), out);
}